// Round 4
// baseline (689.022 us; speedup 1.0000x reference)
//
#include <hip/hip_runtime.h>
#include <stdint.h>
#include <stddef.h>

// ---------------------------------------------------------------------------
// Attention_7284264534326  (B=8, S=2048, D=1024). ALL float tensors are FP32
// (per reference); mask int32; output fp32.
//   q = (x1@wq)*D^-0.5 ; k = x2@wk ; v = x2@wv
//   a = softmax(q@k^T + mask*(-1e9)) ; y = relu(a@v) ; out = y@wo
// Compute path: fp32 -> bf16 (RNE) at boundaries, bf16 MFMA GEMMs (B^T
// layout, explicit uint4 LDS staging), fp32 accumulate, fp32 final output.
// Batch-chunked: ws bytes = 8MB (wT) + nb*28MB.
// ---------------------------------------------------------------------------

typedef __bf16 bf16x8 __attribute__((ext_vector_type(8)));
typedef float  floatx4 __attribute__((ext_vector_type(4)));

__device__ __forceinline__ unsigned short f2bf(float f) {
    unsigned u = __float_as_uint(f);
    return (unsigned short)((u + 0x7FFFu + ((u >> 16) & 1u)) >> 16);  // RNE
}
__device__ __forceinline__ float bf2f(unsigned short h) {
    return __uint_as_float(((unsigned)h) << 16);
}

// ---------------------------------------------------------------------------
// fp32 -> bf16, n % 2048 == 0, one thread per 8 elems
// ---------------------------------------------------------------------------
__global__ __launch_bounds__(256) void cvt_bf16(
    const float* __restrict__ in, unsigned short* __restrict__ out, long long n)
{
    long long i8 = ((long long)blockIdx.x * 256 + threadIdx.x) * 8;
    if (i8 >= n) return;
    float4 a = *(const float4*)(in + i8);
    float4 b = *(const float4*)(in + i8 + 4);
    union { uint4 u; unsigned short h[8]; } o;
    o.h[0] = f2bf(a.x); o.h[1] = f2bf(a.y); o.h[2] = f2bf(a.z); o.h[3] = f2bf(a.w);
    o.h[4] = f2bf(b.x); o.h[5] = f2bf(b.y); o.h[6] = f2bf(b.z); o.h[7] = f2bf(b.w);
    *(uint4*)(out + i8) = o.u;
}

// ---------------------------------------------------------------------------
// fp32 [rows][cols] -> bf16 transposed out[c][r].  rows,cols % 32 == 0.
// ---------------------------------------------------------------------------
__global__ __launch_bounds__(256) void cvt_transpose_w(
    const float* __restrict__ in, unsigned short* __restrict__ out,
    int rows, int cols)
{
    __shared__ unsigned short tile[32][33];
    const int cbase = blockIdx.x * 32;
    const int rbase = blockIdx.y * 32;
#pragma unroll
    for (int i = 0; i < 4; i++) {
        int r = rbase + threadIdx.y + i * 8;
        tile[threadIdx.y + i * 8][threadIdx.x] =
            f2bf(in[(size_t)r * cols + (cbase + threadIdx.x)]);
    }
    __syncthreads();
#pragma unroll
    for (int i = 0; i < 4; i++) {
        int r = cbase + threadIdx.y + i * 8;
        out[(size_t)r * rows + (rbase + threadIdx.x)] =
            tile[threadIdx.x][threadIdx.y + i * 8];
    }
}

// ---------------------------------------------------------------------------
// C[m][n] = scale * sum_k A[m][k] * B[n][k]  (optional relu).
// A,B bf16; C bf16 (F32OUT=0) or fp32 (F32OUT=1).
// 128x128 tile, BK=32, 256 thr (4 waves 2x2, each 64x64 = 4x4 of 16x16x32).
// Explicit staging: tile = 512 16B chunks; thread t stages {t, t+256};
// chunk c -> LDS elems [8c,8c+8) == row c>>2, col (c&3)*8 of [128][32].
// M,N % 128 == 0, K % 32 == 0.
// ---------------------------------------------------------------------------
template <int RELU, int F32OUT>
__global__ __launch_bounds__(256) void gemm_bt(
    const unsigned short* __restrict__ A,
    const unsigned short* __restrict__ B,
    void* __restrict__ Cv,
    int K, int lda, int ldb, int ldc,
    long long sA, long long sB, long long sC,
    float scale)
{
    __shared__ __align__(16) __bf16 As[128 * 32];
    __shared__ __align__(16) __bf16 Bs[128 * 32];

    const int t    = threadIdx.x;
    const int wave = t >> 6;
    const int lane = t & 63;

    A += (long long)blockIdx.z * sA;
    B += (long long)blockIdx.z * sB;

    const int m0 = blockIdx.y * 128;
    const int n0 = blockIdx.x * 128;
    const int wm = (wave >> 1) * 64;
    const int wn = (wave & 1) * 64;

    const int ca = t;              // chunk 0..255
    const int cb = t + 256;        // chunk 256..511
    const int ra = ca >> 2, cac = (ca & 3) * 8;
    const int rb = cb >> 2, cbc = (cb & 3) * 8;

    const unsigned short* AgA = A + (size_t)(m0 + ra) * lda + cac;
    const unsigned short* AgB = A + (size_t)(m0 + rb) * lda + cbc;
    const unsigned short* BgA = B + (size_t)(n0 + ra) * ldb + cac;
    const unsigned short* BgB = B + (size_t)(n0 + rb) * ldb + cbc;

    const int fr = lane & 15;
    const int fk = (lane >> 4) * 8;

    floatx4 acc[4][4];
#pragma unroll
    for (int i = 0; i < 4; i++)
#pragma unroll
        for (int j = 0; j < 4; j++) acc[i][j] = floatx4{0.f, 0.f, 0.f, 0.f};

    for (int k0 = 0; k0 < K; k0 += 32) {
        uint4 va0 = *(const uint4*)(AgA + k0);
        uint4 va1 = *(const uint4*)(AgB + k0);
        uint4 vb0 = *(const uint4*)(BgA + k0);
        uint4 vb1 = *(const uint4*)(BgB + k0);
        __syncthreads();                     // prev iter's LDS reads done
        *(uint4*)(As + ca * 8) = va0;
        *(uint4*)(As + cb * 8) = va1;
        *(uint4*)(Bs + ca * 8) = vb0;
        *(uint4*)(Bs + cb * 8) = vb1;
        __syncthreads();

        bf16x8 af[4], bfv[4];
#pragma unroll
        for (int i = 0; i < 4; i++) {
            af[i]  = *(const bf16x8*)(As + (wm + i * 16 + fr) * 32 + fk);
            bfv[i] = *(const bf16x8*)(Bs + (wn + i * 16 + fr) * 32 + fk);
        }
#pragma unroll
        for (int i = 0; i < 4; i++)
#pragma unroll
            for (int j = 0; j < 4; j++)
                acc[i][j] = __builtin_amdgcn_mfma_f32_16x16x32_bf16(
                    af[i], bfv[j], acc[i][j], 0, 0, 0);
    }

    // C/D layout (m89-verified): col = lane&15, row = (lane>>4)*4 + r
    const int er = (lane >> 4) * 4;
    const int ec = lane & 15;
#pragma unroll
    for (int i = 0; i < 4; i++)
#pragma unroll
        for (int j = 0; j < 4; j++)
#pragma unroll
            for (int r = 0; r < 4; r++) {
                float v = acc[i][j][r] * scale;
                if (RELU) v = fmaxf(v, 0.f);
                size_t row = (size_t)(m0 + wm + i * 16 + er + r);
                size_t col = (size_t)(n0 + wn + j * 16 + ec);
                if (F32OUT) {
                    ((float*)Cv + (long long)blockIdx.z * sC)[row * ldc + col] = v;
                } else {
                    ((unsigned short*)Cv + (long long)blockIdx.z * sC)[row * ldc + col] = f2bf(v);
                }
            }
}

// ---------------------------------------------------------------------------
// In-place masked softmax over bf16 rows (len Sk=2048), fp32 math.
// Masked logits hit exactly -1e9 in fp32 (|s|<32), exp underflows to 0 --
// bit-matches the fp32 numpy reference's mask semantics.
// ---------------------------------------------------------------------------
__global__ __launch_bounds__(256) void softmax_rows(
    unsigned short* __restrict__ S, const int* __restrict__ mask,
    int b0, int Sq, int Sk)
{
    const int row = blockIdx.x;
    const int b   = b0 + row / Sq;
    unsigned short* p  = S + (size_t)row * Sk;
    const int*      mk = mask + (size_t)b * Sk;

    const int t    = threadIdx.x;
    const int wave = t >> 6;
    const int lane = t & 63;

    union { uint4 u; unsigned short h[8]; } lu;
    lu.u = *(const uint4*)(p + t * 8);
    int4 m0 = *(const int4*)(mk + t * 8);
    int4 m1 = *(const int4*)(mk + t * 8 + 4);
    int mi[8] = {m0.x, m0.y, m0.z, m0.w, m1.x, m1.y, m1.z, m1.w};

    float v[8];
    float mx = -3.0e38f;
#pragma unroll
    for (int j = 0; j < 8; j++) {
        v[j] = bf2f(lu.h[j]) + (float)mi[j] * (-1.0e9f);
        mx = fmaxf(mx, v[j]);
    }
#pragma unroll
    for (int o = 32; o > 0; o >>= 1) mx = fmaxf(mx, __shfl_xor(mx, o));

    __shared__ float red[4];
    if (lane == 0) red[wave] = mx;
    __syncthreads();
    mx = fmaxf(fmaxf(red[0], red[1]), fmaxf(red[2], red[3]));

    float sum = 0.f;
#pragma unroll
    for (int j = 0; j < 8; j++) {
        v[j] = __expf(v[j] - mx);
        sum += v[j];
    }
#pragma unroll
    for (int o = 32; o > 0; o >>= 1) sum += __shfl_xor(sum, o);
    __syncthreads();
    if (lane == 0) red[wave] = sum;
    __syncthreads();
    sum = red[0] + red[1] + red[2] + red[3];

    const float inv = 1.0f / sum;
#pragma unroll
    for (int j = 0; j < 8; j++) lu.h[j] = f2bf(v[j] * inv);
    *(uint4*)(p + t * 8) = lu.u;
}

// Diagnostic: future failure with absmax ~1.3 => "ws too small" branch fired.
__global__ void fill_one_f32(float* o, int n) {
    int i = blockIdx.x * 256 + threadIdx.x;
    if (i < n) o[i] = 1.0f;
}

// ---------------------------------------------------------------------------
extern "C" void kernel_launch(void* const* d_in, const int* in_sizes, int n_in,
                              void* d_out, int out_size, void* d_ws, size_t ws_size,
                              hipStream_t stream)
{
    const float* x1   = (const float*)d_in[0];
    const float* x2   = (const float*)d_in[1];
    const int*   mask = (const int*)d_in[2];
    const float* wq   = (const float*)d_in[3];
    const float* wk   = (const float*)d_in[4];
    const float* wv   = (const float*)d_in[5];
    const float* wo   = (const float*)d_in[6];
    float*       out  = (float*)d_out;

    const int S = 2048, D = 1024, Btot = 8;

    // ws bf16 elems = 4*D*D + nb*(5*S*D + S*S):  8MB + nb*28MB bytes
    const size_t WT = (size_t)4 * D * D;
    const size_t PB = (size_t)5 * S * D + (size_t)S * S;   // 14,680,064 elems
    const size_t avail = ws_size / 2;
    int nb = 0;
    if      (WT + 8 * PB <= avail) nb = 8;
    else if (WT + 4 * PB <= avail) nb = 4;
    else if (WT + 2 * PB <= avail) nb = 2;
    else if (WT + 1 * PB <= avail) nb = 1;
    if (nb == 0) {
        fill_one_f32<<<(out_size + 255) / 256, 256, 0, stream>>>(out, out_size);
        return;
    }

    unsigned short* wqT = (unsigned short*)d_ws;
    unsigned short* wkT = wqT + (size_t)D * D;
    unsigned short* wvT = wkT + (size_t)D * D;
    unsigned short* woT = wvT + (size_t)D * D;
    unsigned short* x1b = woT + (size_t)D * D;              // nb*S x D  bf16
    unsigned short* x2b = x1b + (size_t)nb * S * D;         // nb*S x D
    unsigned short* q   = x2b + (size_t)nb * S * D;         // nb*S x D
    unsigned short* kk  = q   + (size_t)nb * S * D;         // nb*S x D
    unsigned short* vT  = kk  + (size_t)nb * S * D;         // D x nb*S
    unsigned short* sc  = vT  + (size_t)nb * S * D;         // nb x S x S
    unsigned short* y   = q;                                // alias (q dead)

    dim3 tb(32, 8);
    cvt_transpose_w<<<dim3(32, 32), tb, 0, stream>>>(wq, wqT, D, D);
    cvt_transpose_w<<<dim3(32, 32), tb, 0, stream>>>(wk, wkT, D, D);
    cvt_transpose_w<<<dim3(32, 32), tb, 0, stream>>>(wv, wvT, D, D);
    cvt_transpose_w<<<dim3(32, 32), tb, 0, stream>>>(wo, woT, D, D);

    const int BSc = nb * S;                                 // rows per chunk
    const long long NE = (long long)BSc * D;                // elems per chunk
    for (int c0 = 0; c0 < Btot; c0 += nb) {
        const float* x1c = x1 + (size_t)c0 * S * D;
        const float* x2c = x2 + (size_t)c0 * S * D;

        cvt_bf16<<<(int)(NE / 2048), 256, 0, stream>>>(x1c, x1b, NE);
        cvt_bf16<<<(int)(NE / 2048), 256, 0, stream>>>(x2c, x2b, NE);

        // q = x1b @ wqT^T * D^-0.5 ; k = x2b @ wkT^T
        gemm_bt<0, 0><<<dim3(D / 128, BSc / 128, 1), 256, 0, stream>>>(
            x1b, wqT, q, D, D, D, D, 0, 0, 0, 0.03125f);
        gemm_bt<0, 0><<<dim3(D / 128, BSc / 128, 1), 256, 0, stream>>>(
            x2b, wkT, kk, D, D, D, D, 0, 0, 0, 1.0f);
        // vT[e][s] = sum_d wvT[e][d] * x2b[s][d]   (D x BSc)
        gemm_bt<0, 0><<<dim3(BSc / 128, D / 128, 1), 256, 0, stream>>>(
            wvT, x2b, vT, D, D, D, BSc, 0, 0, 0, 1.0f);

        // scores[z] = q_z @ k_z^T
        gemm_bt<0, 0><<<dim3(S / 128, S / 128, nb), 256, 0, stream>>>(
            q, kk, sc, D, D, D, S,
            (long long)S * D, (long long)S * D, (long long)S * S, 1.0f);

        // masked softmax in place
        softmax_rows<<<BSc, 256, 0, stream>>>(sc, mask, c0, S, S);

        // y[z] = relu(P_z @ v_z) : B^T = vT (batch cols start z*S, ldb=BSc)
        gemm_bt<1, 0><<<dim3(D / 128, S / 128, nb), 256, 0, stream>>>(
            sc, vT, y, S, S, BSc, D,
            (long long)S * S, (long long)S, (long long)S * D, 1.0f);

        // out_chunk = y @ woT^T   (fp32 output)
        gemm_bt<0, 1><<<dim3(D / 128, BSc / 128, 1), 256, 0, stream>>>(
            y, woT, out + (size_t)c0 * S * D, D, D, D, D, 0, 0, 0, 1.0f);
    }
}

// Round 5
// 669.386 us; speedup vs baseline: 1.0293x; 1.0293x over previous
//
#include <hip/hip_runtime.h>
#include <stdint.h>
#include <stddef.h>

// ---------------------------------------------------------------------------
// Attention_7284264534326  (B=8, S=2048, D=1024). fp32 tensors, int32 mask,
// fp32 output.
//   q = (x1@wq)*D^-0.5 ; k = x2@wk ; v = x2@wv
//   a = softmax(q@k^T + mask*(-1e9)) ; y = relu(a@v) ; out = y@wo
// fp32 -> bf16 (RNE) at boundaries; bf16 MFMA GEMMs in m97 structure
// (128x128 tile, BK=32, global_load_lds width-16 async staging -- verified
// 874 TF vs 517 TF explicit staging); fp32 accumulate; fp32 final output.
// R4 (explicit staging) measured 474 TF/GEMM, MfmaUtil 20%, VALUBusy 31% --
// staging VALU-bound, exactly the m93 plateau. This round: the m93->m97 step.
// Batch-chunked: ws bytes = 8MB (wT) + nb*28MB.
// ---------------------------------------------------------------------------

typedef __bf16 bf16x8 __attribute__((ext_vector_type(8)));
typedef float  floatx4 __attribute__((ext_vector_type(4)));

__device__ __forceinline__ unsigned short f2bf(float f) {
    unsigned u = __float_as_uint(f);
    return (unsigned short)((u + 0x7FFFu + ((u >> 16) & 1u)) >> 16);  // RNE
}
__device__ __forceinline__ float bf2f(unsigned short h) {
    return __uint_as_float(((unsigned)h) << 16);
}

__device__ __forceinline__ void async16(const void* g, void* l) {
    __builtin_amdgcn_global_load_lds(
        (const __attribute__((address_space(1))) unsigned int*)g,
        (__attribute__((address_space(3))) unsigned int*)l, 16, 0, 0);
}

// ---------------------------------------------------------------------------
// fp32 -> bf16, n % 2048 == 0, one thread per 8 elems
// ---------------------------------------------------------------------------
__global__ __launch_bounds__(256) void cvt_bf16(
    const float* __restrict__ in, unsigned short* __restrict__ out, long long n)
{
    long long i8 = ((long long)blockIdx.x * 256 + threadIdx.x) * 8;
    if (i8 >= n) return;
    float4 a = *(const float4*)(in + i8);
    float4 b = *(const float4*)(in + i8 + 4);
    union { uint4 u; unsigned short h[8]; } o;
    o.h[0] = f2bf(a.x); o.h[1] = f2bf(a.y); o.h[2] = f2bf(a.z); o.h[3] = f2bf(a.w);
    o.h[4] = f2bf(b.x); o.h[5] = f2bf(b.y); o.h[6] = f2bf(b.z); o.h[7] = f2bf(b.w);
    *(uint4*)(out + i8) = o.u;
}

// ---------------------------------------------------------------------------
// fp32 [rows][cols] -> bf16 transposed out[c][r].  rows,cols % 32 == 0.
// ---------------------------------------------------------------------------
__global__ __launch_bounds__(256) void cvt_transpose_w(
    const float* __restrict__ in, unsigned short* __restrict__ out,
    int rows, int cols)
{
    __shared__ unsigned short tile[32][33];
    const int cbase = blockIdx.x * 32;
    const int rbase = blockIdx.y * 32;
#pragma unroll
    for (int i = 0; i < 4; i++) {
        int r = rbase + threadIdx.y + i * 8;
        tile[threadIdx.y + i * 8][threadIdx.x] =
            f2bf(in[(size_t)r * cols + (cbase + threadIdx.x)]);
    }
    __syncthreads();
#pragma unroll
    for (int i = 0; i < 4; i++) {
        int r = cbase + threadIdx.y + i * 8;
        out[(size_t)r * rows + (rbase + threadIdx.x)] =
            tile[threadIdx.x][threadIdx.y + i * 8];
    }
}

// ---------------------------------------------------------------------------
// C[m][n] = scale * sum_k A[m][k] * B[n][k]  (optional relu).
// A,B bf16; C bf16 (F32OUT=0) or fp32 (F32OUT=1).
// m97 structure: 128x128 tile, BK=32, 4 waves (2x2, each 64x64 = 4x4 MFMA of
// 16x16x32). global_load_lds width-16: LDS dest is wave-uniform base +
// lane*16; tile stored unpadded row-major [128][32]; chunk c (16B) -> row
// c>>2, col (c&3)*8; wave w stages chunks [w*128, w*128+128) in two rounds.
// M,N % 128 == 0, K % 32 == 0.
// ---------------------------------------------------------------------------
template <int RELU, int F32OUT>
__global__ __launch_bounds__(256) void gemm_bt(
    const unsigned short* __restrict__ A,
    const unsigned short* __restrict__ B,
    void* __restrict__ Cv,
    int K, int lda, int ldb, int ldc,
    long long sA, long long sB, long long sC,
    float scale)
{
    __shared__ __align__(16) __bf16 As[128 * 32];
    __shared__ __align__(16) __bf16 Bs[128 * 32];

    const int t    = threadIdx.x;
    const int wave = t >> 6;
    const int lane = t & 63;

    A += (long long)blockIdx.z * sA;
    B += (long long)blockIdx.z * sB;

    const int m0 = blockIdx.y * 128;
    const int n0 = blockIdx.x * 128;
    const int wm = (wave >> 1) * 64;
    const int wn = (wave & 1) * 64;

    // staging chunks: wave covers [wave*128, wave*128+128), lane strides 16B
    const int c0  = wave * 128 + lane;
    const int c1  = c0 + 64;
    const int ar0 = c0 >> 2, ac0 = (c0 & 3) * 8;
    const int ar1 = c1 >> 2, ac1 = (c1 & 3) * 8;

    __bf16* ldsA0 = As + wave * 1024;          // wave-uniform LDS bases
    __bf16* ldsA1 = As + wave * 1024 + 512;
    __bf16* ldsB0 = Bs + wave * 1024;
    __bf16* ldsB1 = Bs + wave * 1024 + 512;

    const unsigned short* Ag0 = A + (size_t)(m0 + ar0) * lda + ac0;
    const unsigned short* Ag1 = A + (size_t)(m0 + ar1) * lda + ac1;
    const unsigned short* Bg0 = B + (size_t)(n0 + ar0) * ldb + ac0;
    const unsigned short* Bg1 = B + (size_t)(n0 + ar1) * ldb + ac1;

    const int fr = lane & 15;
    const int fk = (lane >> 4) * 8;

    floatx4 acc[4][4];
#pragma unroll
    for (int i = 0; i < 4; i++)
#pragma unroll
        for (int j = 0; j < 4; j++) acc[i][j] = floatx4{0.f, 0.f, 0.f, 0.f};

    for (int k0 = 0; k0 < K; k0 += 32) {
        __syncthreads();                 // prev iter's LDS reads done
        async16(Ag0 + k0, ldsA0);
        async16(Ag1 + k0, ldsA1);
        async16(Bg0 + k0, ldsB0);
        async16(Bg1 + k0, ldsB1);
        __syncthreads();                 // compiler drains vmcnt before barrier

        bf16x8 af[4], bfv[4];
#pragma unroll
        for (int i = 0; i < 4; i++) {
            af[i]  = *(const bf16x8*)(As + (wm + i * 16 + fr) * 32 + fk);
            bfv[i] = *(const bf16x8*)(Bs + (wn + i * 16 + fr) * 32 + fk);
        }
#pragma unroll
        for (int i = 0; i < 4; i++)
#pragma unroll
            for (int j = 0; j < 4; j++)
                acc[i][j] = __builtin_amdgcn_mfma_f32_16x16x32_bf16(
                    af[i], bfv[j], acc[i][j], 0, 0, 0);
    }

    // C/D layout (m89-verified): col = lane&15, row = (lane>>4)*4 + r
    const int er = (lane >> 4) * 4;
    const int ec = lane & 15;
#pragma unroll
    for (int i = 0; i < 4; i++)
#pragma unroll
        for (int j = 0; j < 4; j++)
#pragma unroll
            for (int r = 0; r < 4; r++) {
                float v = acc[i][j][r] * scale;
                if (RELU) v = fmaxf(v, 0.f);
                size_t row = (size_t)(m0 + wm + i * 16 + er + r);
                size_t col = (size_t)(n0 + wn + j * 16 + ec);
                if (F32OUT) {
                    ((float*)Cv + (long long)blockIdx.z * sC)[row * ldc + col] = v;
                } else {
                    ((unsigned short*)Cv + (long long)blockIdx.z * sC)[row * ldc + col] = f2bf(v);
                }
            }
}

// ---------------------------------------------------------------------------
// In-place masked softmax over bf16 rows (len Sk=2048), fp32 math.
// ---------------------------------------------------------------------------
__global__ __launch_bounds__(256) void softmax_rows(
    unsigned short* __restrict__ S, const int* __restrict__ mask,
    int b0, int Sq, int Sk)
{
    const int row = blockIdx.x;
    const int b   = b0 + row / Sq;
    unsigned short* p  = S + (size_t)row * Sk;
    const int*      mk = mask + (size_t)b * Sk;

    const int t    = threadIdx.x;
    const int wave = t >> 6;
    const int lane = t & 63;

    union { uint4 u; unsigned short h[8]; } lu;
    lu.u = *(const uint4*)(p + t * 8);
    int4 m0 = *(const int4*)(mk + t * 8);
    int4 m1 = *(const int4*)(mk + t * 8 + 4);
    int mi[8] = {m0.x, m0.y, m0.z, m0.w, m1.x, m1.y, m1.z, m1.w};

    float v[8];
    float mx = -3.0e38f;
#pragma unroll
    for (int j = 0; j < 8; j++) {
        v[j] = bf2f(lu.h[j]) + (float)mi[j] * (-1.0e9f);
        mx = fmaxf(mx, v[j]);
    }
#pragma unroll
    for (int o = 32; o > 0; o >>= 1) mx = fmaxf(mx, __shfl_xor(mx, o));

    __shared__ float red[4];
    if (lane == 0) red[wave] = mx;
    __syncthreads();
    mx = fmaxf(fmaxf(red[0], red[1]), fmaxf(red[2], red[3]));

    float sum = 0.f;
#pragma unroll
    for (int j = 0; j < 8; j++) {
        v[j] = __expf(v[j] - mx);
        sum += v[j];
    }
#pragma unroll
    for (int o = 32; o > 0; o >>= 1) sum += __shfl_xor(sum, o);
    __syncthreads();
    if (lane == 0) red[wave] = sum;
    __syncthreads();
    sum = red[0] + red[1] + red[2] + red[3];

    const float inv = 1.0f / sum;
#pragma unroll
    for (int j = 0; j < 8; j++) lu.h[j] = f2bf(v[j] * inv);
    *(uint4*)(p + t * 8) = lu.u;
}

// Diagnostic: future failure with absmax ~1.3 => "ws too small" branch fired.
__global__ void fill_one_f32(float* o, int n) {
    int i = blockIdx.x * 256 + threadIdx.x;
    if (i < n) o[i] = 1.0f;
}

// ---------------------------------------------------------------------------
extern "C" void kernel_launch(void* const* d_in, const int* in_sizes, int n_in,
                              void* d_out, int out_size, void* d_ws, size_t ws_size,
                              hipStream_t stream)
{
    const float* x1   = (const float*)d_in[0];
    const float* x2   = (const float*)d_in[1];
    const int*   mask = (const int*)d_in[2];
    const float* wq   = (const float*)d_in[3];
    const float* wk   = (const float*)d_in[4];
    const float* wv   = (const float*)d_in[5];
    const float* wo   = (const float*)d_in[6];
    float*       out  = (float*)d_out;

    const int S = 2048, D = 1024, Btot = 8;

    // ws bf16 elems = 4*D*D + nb*(5*S*D + S*S):  8MB + nb*28MB bytes
    const size_t WT = (size_t)4 * D * D;
    const size_t PB = (size_t)5 * S * D + (size_t)S * S;
    const size_t avail = ws_size / 2;
    int nb = 0;
    if      (WT + 8 * PB <= avail) nb = 8;
    else if (WT + 4 * PB <= avail) nb = 4;
    else if (WT + 2 * PB <= avail) nb = 2;
    else if (WT + 1 * PB <= avail) nb = 1;
    if (nb == 0) {
        fill_one_f32<<<(out_size + 255) / 256, 256, 0, stream>>>(out, out_size);
        return;
    }

    unsigned short* wqT = (unsigned short*)d_ws;
    unsigned short* wkT = wqT + (size_t)D * D;
    unsigned short* wvT = wkT + (size_t)D * D;
    unsigned short* woT = wvT + (size_t)D * D;
    unsigned short* x1b = woT + (size_t)D * D;              // nb*S x D  bf16
    unsigned short* x2b = x1b + (size_t)nb * S * D;         // nb*S x D
    unsigned short* q   = x2b + (size_t)nb * S * D;         // nb*S x D
    unsigned short* kk  = q   + (size_t)nb * S * D;         // nb*S x D
    unsigned short* vT  = kk  + (size_t)nb * S * D;         // D x nb*S
    unsigned short* sc  = vT  + (size_t)nb * S * D;         // nb x S x S
    unsigned short* y   = q;                                // alias (q dead)

    dim3 tb(32, 8);
    cvt_transpose_w<<<dim3(32, 32), tb, 0, stream>>>(wq, wqT, D, D);
    cvt_transpose_w<<<dim3(32, 32), tb, 0, stream>>>(wk, wkT, D, D);
    cvt_transpose_w<<<dim3(32, 32), tb, 0, stream>>>(wv, wvT, D, D);
    cvt_transpose_w<<<dim3(32, 32), tb, 0, stream>>>(wo, woT, D, D);

    const int BSc = nb * S;                                 // rows per chunk
    const long long NE = (long long)BSc * D;                // elems per chunk
    for (int c0 = 0; c0 < Btot; c0 += nb) {
        const float* x1c = x1 + (size_t)c0 * S * D;
        const float* x2c = x2 + (size_t)c0 * S * D;

        cvt_bf16<<<(int)(NE / 2048), 256, 0, stream>>>(x1c, x1b, NE);
        cvt_bf16<<<(int)(NE / 2048), 256, 0, stream>>>(x2c, x2b, NE);

        // q = x1b @ wqT^T * D^-0.5 ; k = x2b @ wkT^T
        gemm_bt<0, 0><<<dim3(D / 128, BSc / 128, 1), 256, 0, stream>>>(
            x1b, wqT, q, D, D, D, D, 0, 0, 0, 0.03125f);
        gemm_bt<0, 0><<<dim3(D / 128, BSc / 128, 1), 256, 0, stream>>>(
            x2b, wkT, kk, D, D, D, D, 0, 0, 0, 1.0f);
        // vT[e][s] = sum_d wvT[e][d] * x2b[s][d]   (D x BSc)
        gemm_bt<0, 0><<<dim3(BSc / 128, D / 128, 1), 256, 0, stream>>>(
            wvT, x2b, vT, D, D, D, BSc, 0, 0, 0, 1.0f);

        // scores[z] = q_z @ k_z^T
        gemm_bt<0, 0><<<dim3(S / 128, S / 128, nb), 256, 0, stream>>>(
            q, kk, sc, D, D, D, S,
            (long long)S * D, (long long)S * D, (long long)S * S, 1.0f);

        // masked softmax in place
        softmax_rows<<<BSc, 256, 0, stream>>>(sc, mask, c0, S, S);

        // y[z] = relu(P_z @ v_z) : B^T = vT (batch cols start z*S, ldb=BSc)
        gemm_bt<1, 0><<<dim3(D / 128, S / 128, nb), 256, 0, stream>>>(
            sc, vT, y, S, S, BSc, D,
            (long long)S * S, (long long)S, (long long)S * D, 1.0f);

        // out_chunk = y @ woT^T   (fp32 output)
        gemm_bt<0, 1><<<dim3(D / 128, BSc / 128, 1), 256, 0, stream>>>(
            y, woT, out + (size_t)c0 * S * D, D, D, D, D, 0, 0, 0, 1.0f);
    }
}

// Round 6
// 634.319 us; speedup vs baseline: 1.0862x; 1.0553x over previous
//
#include <hip/hip_runtime.h>
#include <stdint.h>
#include <stddef.h>

// ---------------------------------------------------------------------------
// Attention_7284264534326  (B=8, S=2048, D=1024). fp32 tensors, int32 mask,
// fp32 output.
//   q = (x1@wq)*D^-0.5 ; k = x2@wk ; v = x2@wv
//   a = softmax(q@k^T + mask*(-1e9)) ; y = relu(a@v) ; out = y@wo
// bf16 MFMA GEMMs (m97 structure, async global_load_lds width-16).
// R6 changes vs R5 (which measured 537 TF/GEMM, MfmaUtil 22%, 8.4M LDS bank
// conflict cycles, 285 MB HBM fetch vs 64 MB ideal):
//  1. XCD-aware 1-D block swizzle: batch -> XCD (id%8), 4x4 supertiles
//     within batch; M-band-per-XCD for unbatched projections.
//  2. Bank-permuted LDS staging: slot s stages global chunk
//     (r=s>>2, c=(s&3)^((r>>1)&3)); fragment reads un-permute. Turns the
//     4-8-way ds_read_b128 conflicts into free 2-way (m136).
// Same data, same MFMA order -> bit-identical output to R5.
// ---------------------------------------------------------------------------

typedef __bf16 bf16x8 __attribute__((ext_vector_type(8)));
typedef float  floatx4 __attribute__((ext_vector_type(4)));

__device__ __forceinline__ unsigned short f2bf(float f) {
    unsigned u = __float_as_uint(f);
    return (unsigned short)((u + 0x7FFFu + ((u >> 16) & 1u)) >> 16);  // RNE
}
__device__ __forceinline__ float bf2f(unsigned short h) {
    return __uint_as_float(((unsigned)h) << 16);
}

__device__ __forceinline__ void async16(const void* g, void* l) {
    __builtin_amdgcn_global_load_lds(
        (const __attribute__((address_space(1))) unsigned int*)g,
        (__attribute__((address_space(3))) unsigned int*)l, 16, 0, 0);
}

// ---------------------------------------------------------------------------
// fp32 -> bf16, n % 2048 == 0
// ---------------------------------------------------------------------------
__global__ __launch_bounds__(256) void cvt_bf16(
    const float* __restrict__ in, unsigned short* __restrict__ out, long long n)
{
    long long i8 = ((long long)blockIdx.x * 256 + threadIdx.x) * 8;
    if (i8 >= n) return;
    float4 a = *(const float4*)(in + i8);
    float4 b = *(const float4*)(in + i8 + 4);
    union { uint4 u; unsigned short h[8]; } o;
    o.h[0] = f2bf(a.x); o.h[1] = f2bf(a.y); o.h[2] = f2bf(a.z); o.h[3] = f2bf(a.w);
    o.h[4] = f2bf(b.x); o.h[5] = f2bf(b.y); o.h[6] = f2bf(b.z); o.h[7] = f2bf(b.w);
    *(uint4*)(out + i8) = o.u;
}

// ---------------------------------------------------------------------------
// fp32 [rows][cols] -> bf16 transposed out[c][r].  rows,cols % 32 == 0.
// ---------------------------------------------------------------------------
__global__ __launch_bounds__(256) void cvt_transpose_w(
    const float* __restrict__ in, unsigned short* __restrict__ out,
    int rows, int cols)
{
    __shared__ unsigned short tile[32][33];
    const int cbase = blockIdx.x * 32;
    const int rbase = blockIdx.y * 32;
#pragma unroll
    for (int i = 0; i < 4; i++) {
        int r = rbase + threadIdx.y + i * 8;
        tile[threadIdx.y + i * 8][threadIdx.x] =
            f2bf(in[(size_t)r * cols + (cbase + threadIdx.x)]);
    }
    __syncthreads();
#pragma unroll
    for (int i = 0; i < 4; i++) {
        int r = cbase + threadIdx.y + i * 8;
        out[(size_t)r * rows + (rbase + threadIdx.x)] =
            tile[threadIdx.x][threadIdx.y + i * 8];
    }
}

// ---------------------------------------------------------------------------
// C[m][n] = scale * sum_k A[m][k] * B[n][k]  (optional relu).
// A,B bf16; C bf16 (F32OUT=0) or fp32 (F32OUT=1).
// 1-D grid of gx*gy*gz blocks; decode:
//   gz>1 : bz = id%gz (batch->XCD), tile walked in 4x4 supertiles
//          (needs gx%4==0, gy%4==0, (gx*gy)%16==0)
//   gz==1: XCD m-banding: by = (id%8)*(gy/8) + (id/8)/gx, bx = (id/8)%gx
//          (needs gy%8==0)
// LDS: bank-permuted slots (see header comment). M,N %128==0, K%32==0.
// ---------------------------------------------------------------------------
template <int RELU, int F32OUT>
__global__ __launch_bounds__(256) void gemm_bt(
    const unsigned short* __restrict__ A,
    const unsigned short* __restrict__ B,
    void* __restrict__ Cv,
    int K, int lda, int ldb, int ldc,
    long long sA, long long sB, long long sC,
    float scale, int gx, int gy, int gz)
{
    __shared__ __align__(16) __bf16 As[128 * 32];
    __shared__ __align__(16) __bf16 Bs[128 * 32];

    const int t    = threadIdx.x;
    const int wave = t >> 6;
    const int lane = t & 63;

    // ---- block swizzle ----
    int id = blockIdx.x;
    int bz, bx, by;
    if (gz > 1) {
        bz = id % gz;                      // batch pinned to XCD (id%8)
        int tt  = id / gz;
        int stw = gx >> 2;
        int st  = tt >> 4, lt = tt & 15;   // 4x4 supertile
        bx = (st % stw) * 4 + (lt & 3);
        by = (st / stw) * 4 + (lt >> 2);
    } else {
        bz = 0;
        int band = gy >> 3;
        int q = id >> 3, x7 = id & 7;      // XCD x7 gets contiguous m-band
        by = x7 * band + q / gx;
        bx = q % gx;
    }

    A += (long long)bz * sA;
    B += (long long)bz * sB;

    const int m0 = by * 128;
    const int n0 = bx * 128;
    const int wm = (wave >> 1) * 64;
    const int wn = (wave & 1) * 64;

    // ---- staging with bank permute ----
    // slot s holds global chunk (r = s>>2, c = (s&3) ^ ((r>>1)&3))
    const int s0  = wave * 128 + lane;
    const int s1  = s0 + 64;
    const int ar0 = s0 >> 2, ac0 = ((s0 & 3) ^ ((ar0 >> 1) & 3)) * 8;
    const int ar1 = s1 >> 2, ac1 = ((s1 & 3) ^ ((ar1 >> 1) & 3)) * 8;

    __bf16* ldsA0 = As + wave * 1024;          // wave-uniform LDS bases
    __bf16* ldsA1 = As + wave * 1024 + 512;
    __bf16* ldsB0 = Bs + wave * 1024;
    __bf16* ldsB1 = Bs + wave * 1024 + 512;

    const unsigned short* Ag0 = A + (size_t)(m0 + ar0) * lda + ac0;
    const unsigned short* Ag1 = A + (size_t)(m0 + ar1) * lda + ac1;
    const unsigned short* Bg0 = B + (size_t)(n0 + ar0) * ldb + ac0;
    const unsigned short* Bg1 = B + (size_t)(n0 + ar1) * ldb + ac1;

    // ---- fragment addressing (un-permute; wave-constant per lane) ----
    const int fr = lane & 15;
    const int fj = lane >> 4;
    const int kx = (fj ^ ((fr >> 1) & 3)) * 8;

    floatx4 acc[4][4];
#pragma unroll
    for (int i = 0; i < 4; i++)
#pragma unroll
        for (int j = 0; j < 4; j++) acc[i][j] = floatx4{0.f, 0.f, 0.f, 0.f};

    for (int k0 = 0; k0 < K; k0 += 32) {
        __syncthreads();                 // prev iter's LDS reads done
        async16(Ag0 + k0, ldsA0);
        async16(Ag1 + k0, ldsA1);
        async16(Bg0 + k0, ldsB0);
        async16(Bg1 + k0, ldsB1);
        __syncthreads();                 // vmcnt drained before barrier

        bf16x8 af[4], bfv[4];
#pragma unroll
        for (int i = 0; i < 4; i++) {
            af[i]  = *(const bf16x8*)(As + (wm + i * 16 + fr) * 32 + kx);
            bfv[i] = *(const bf16x8*)(Bs + (wn + i * 16 + fr) * 32 + kx);
        }
#pragma unroll
        for (int i = 0; i < 4; i++)
#pragma unroll
            for (int j = 0; j < 4; j++)
                acc[i][j] = __builtin_amdgcn_mfma_f32_16x16x32_bf16(
                    af[i], bfv[j], acc[i][j], 0, 0, 0);
    }

    // C/D layout (m89-verified): col = lane&15, row = (lane>>4)*4 + r
    const int er = (lane >> 4) * 4;
    const int ec = lane & 15;
#pragma unroll
    for (int i = 0; i < 4; i++)
#pragma unroll
        for (int j = 0; j < 4; j++)
#pragma unroll
            for (int r = 0; r < 4; r++) {
                float v = acc[i][j][r] * scale;
                if (RELU) v = fmaxf(v, 0.f);
                size_t row = (size_t)(m0 + wm + i * 16 + er + r);
                size_t col = (size_t)(n0 + wn + j * 16 + ec);
                if (F32OUT) {
                    ((float*)Cv + (long long)bz * sC)[row * ldc + col] = v;
                } else {
                    ((unsigned short*)Cv + (long long)bz * sC)[row * ldc + col] = f2bf(v);
                }
            }
}

// ---------------------------------------------------------------------------
// In-place masked softmax over bf16 rows (len Sk=2048), fp32 math.
// ---------------------------------------------------------------------------
__global__ __launch_bounds__(256) void softmax_rows(
    unsigned short* __restrict__ S, const int* __restrict__ mask,
    int b0, int Sq, int Sk)
{
    const int row = blockIdx.x;
    const int b   = b0 + row / Sq;
    unsigned short* p  = S + (size_t)row * Sk;
    const int*      mk = mask + (size_t)b * Sk;

    const int t    = threadIdx.x;
    const int wave = t >> 6;
    const int lane = t & 63;

    union { uint4 u; unsigned short h[8]; } lu;
    lu.u = *(const uint4*)(p + t * 8);
    int4 m0 = *(const int4*)(mk + t * 8);
    int4 m1 = *(const int4*)(mk + t * 8 + 4);
    int mi[8] = {m0.x, m0.y, m0.z, m0.w, m1.x, m1.y, m1.z, m1.w};

    float v[8];
    float mx = -3.0e38f;
#pragma unroll
    for (int j = 0; j < 8; j++) {
        v[j] = bf2f(lu.h[j]) + (float)mi[j] * (-1.0e9f);
        mx = fmaxf(mx, v[j]);
    }
#pragma unroll
    for (int o = 32; o > 0; o >>= 1) mx = fmaxf(mx, __shfl_xor(mx, o));

    __shared__ float red[4];
    if (lane == 0) red[wave] = mx;
    __syncthreads();
    mx = fmaxf(fmaxf(red[0], red[1]), fmaxf(red[2], red[3]));

    float sum = 0.f;
#pragma unroll
    for (int j = 0; j < 8; j++) {
        v[j] = __expf(v[j] - mx);
        sum += v[j];
    }
#pragma unroll
    for (int o = 32; o > 0; o >>= 1) sum += __shfl_xor(sum, o);
    __syncthreads();
    if (lane == 0) red[wave] = sum;
    __syncthreads();
    sum = red[0] + red[1] + red[2] + red[3];

    const float inv = 1.0f / sum;
#pragma unroll
    for (int j = 0; j < 8; j++) lu.h[j] = f2bf(v[j] * inv);
    *(uint4*)(p + t * 8) = lu.u;
}

// Diagnostic: future failure with absmax ~1.3 => "ws too small" branch fired.
__global__ void fill_one_f32(float* o, int n) {
    int i = blockIdx.x * 256 + threadIdx.x;
    if (i < n) o[i] = 1.0f;
}

// ---------------------------------------------------------------------------
extern "C" void kernel_launch(void* const* d_in, const int* in_sizes, int n_in,
                              void* d_out, int out_size, void* d_ws, size_t ws_size,
                              hipStream_t stream)
{
    const float* x1   = (const float*)d_in[0];
    const float* x2   = (const float*)d_in[1];
    const int*   mask = (const int*)d_in[2];
    const float* wq   = (const float*)d_in[3];
    const float* wk   = (const float*)d_in[4];
    const float* wv   = (const float*)d_in[5];
    const float* wo   = (const float*)d_in[6];
    float*       out  = (float*)d_out;

    const int S = 2048, D = 1024, Btot = 8;

    // ws bf16 elems = 4*D*D + nb*(5*S*D + S*S):  8MB + nb*28MB bytes
    const size_t WT = (size_t)4 * D * D;
    const size_t PB = (size_t)5 * S * D + (size_t)S * S;
    const size_t avail = ws_size / 2;
    int nb = 0;
    if      (WT + 8 * PB <= avail) nb = 8;
    else if (WT + 4 * PB <= avail) nb = 4;
    else if (WT + 2 * PB <= avail) nb = 2;
    else if (WT + 1 * PB <= avail) nb = 1;
    if (nb == 0) {
        fill_one_f32<<<(out_size + 255) / 256, 256, 0, stream>>>(out, out_size);
        return;
    }

    unsigned short* wqT = (unsigned short*)d_ws;
    unsigned short* wkT = wqT + (size_t)D * D;
    unsigned short* wvT = wkT + (size_t)D * D;
    unsigned short* woT = wvT + (size_t)D * D;
    unsigned short* x1b = woT + (size_t)D * D;              // nb*S x D  bf16
    unsigned short* x2b = x1b + (size_t)nb * S * D;         // nb*S x D
    unsigned short* q   = x2b + (size_t)nb * S * D;         // nb*S x D
    unsigned short* kk  = q   + (size_t)nb * S * D;         // nb*S x D
    unsigned short* vT  = kk  + (size_t)nb * S * D;         // D x nb*S
    unsigned short* sc  = vT  + (size_t)nb * S * D;         // nb x S x S
    unsigned short* y   = q;                                // alias (q dead)

    dim3 tb(32, 8);
    cvt_transpose_w<<<dim3(32, 32), tb, 0, stream>>>(wq, wqT, D, D);
    cvt_transpose_w<<<dim3(32, 32), tb, 0, stream>>>(wk, wkT, D, D);
    cvt_transpose_w<<<dim3(32, 32), tb, 0, stream>>>(wv, wvT, D, D);
    cvt_transpose_w<<<dim3(32, 32), tb, 0, stream>>>(wo, woT, D, D);

    const int BSc = nb * S;                                 // rows per chunk
    const int MT  = BSc / 128;                              // m-tiles per chunk
    const long long NE = (long long)BSc * D;                // elems per chunk
    for (int c0 = 0; c0 < Btot; c0 += nb) {
        const float* x1c = x1 + (size_t)c0 * S * D;
        const float* x2c = x2 + (size_t)c0 * S * D;

        cvt_bf16<<<(int)(NE / 2048), 256, 0, stream>>>(x1c, x1b, NE);
        cvt_bf16<<<(int)(NE / 2048), 256, 0, stream>>>(x2c, x2b, NE);

        // q = x1b @ wqT^T * D^-0.5     (gx=8 n-tiles, gy=MT m-tiles)
        gemm_bt<0, 0><<<8 * MT, 256, 0, stream>>>(
            x1b, wqT, q, D, D, D, D, 0, 0, 0, 0.03125f, 8, MT, 1);
        // k = x2b @ wkT^T
        gemm_bt<0, 0><<<8 * MT, 256, 0, stream>>>(
            x2b, wkT, kk, D, D, D, D, 0, 0, 0, 1.0f, 8, MT, 1);
        // vT[e][s] = sum_d wvT[e][d] * x2b[s][d]   (D x BSc; gx=MT, gy=8)
        gemm_bt<0, 0><<<MT * 8, 256, 0, stream>>>(
            wvT, x2b, vT, D, D, D, BSc, 0, 0, 0, 1.0f, MT, 8, 1);

        // scores[z] = q_z @ k_z^T   (gx=16, gy=16, gz=nb)
        gemm_bt<0, 0><<<16 * 16 * nb, 256, 0, stream>>>(
            q, kk, sc, D, D, D, S,
            (long long)S * D, (long long)S * D, (long long)S * S, 1.0f,
            16, 16, nb);

        // masked softmax in place
        softmax_rows<<<BSc, 256, 0, stream>>>(sc, mask, c0, S, S);

        // y[z] = relu(P_z @ v_z) : B^T = vT (batch cols z*S, ldb=BSc)
        gemm_bt<1, 0><<<8 * 16 * nb, 256, 0, stream>>>(
            sc, vT, y, S, S, BSc, D,
            (long long)S * S, (long long)S, (long long)S * D, 1.0f,
            8, 16, nb);

        // out_chunk = y @ woT^T   (fp32 output)
        gemm_bt<0, 1><<<8 * MT, 256, 0, stream>>>(
            y, woT, out + (size_t)c0 * S * D, D, D, D, D, 0, 0, 0, 1.0f,
            8, MT, 1);
    }
}